// Round 3
// baseline (368.628 us; speedup 1.0000x reference)
//
#include <hip/hip_runtime.h>
#include <math.h>

#define N_CH 128
#define NB_MAX 512          // max bucket count (n_nodes <= 16384 -> nb <= 512)
#define BIN_CHUNK 4096
#define BIN_T 512
#define BM_T 512
#define BM_CAP 4096

// order-preserving float <-> uint key (unsigned compare == float compare)
__device__ inline unsigned int fkey(float f) {
    unsigned int b = __float_as_uint(f);
    return (b & 0x80000000u) ? ~b : (b | 0x80000000u);
}
__device__ inline float keyf(unsigned int k) {
    unsigned int b = (k & 0x80000000u) ? (k & 0x7FFFFFFFu) : ~k;
    return __uint_as_float(b);
}
#define NEG_INF_KEY 0x007FFFFFu   // fkey(-inf)

// ---------------------------------------------------------------------------
// K0: V1t[k*128+o] = W[o][k] - W[o][128+k], V2t[k*128+o] = W[o][128+k];
//     zero bucket histogram.
// ---------------------------------------------------------------------------
__global__ __launch_bounds__(256) void prep_kernel(const float* __restrict__ W,
                                                   float* __restrict__ V1,
                                                   float* __restrict__ V2,
                                                   int* __restrict__ binCount,
                                                   int nb) {
    int i = blockIdx.x * 256 + threadIdx.x;
    if (i < N_CH * N_CH) {
        int k = i >> 7, o = i & 127;
        float w1 = W[o * 256 + k];
        float w2 = W[o * 256 + 128 + k];
        V1[i] = w1 - w2;
        V2[i] = w2;
    }
    if (i < nb) binCount[i] = 0;
}

// ---------------------------------------------------------------------------
// K1: A = x @ V1 + bias (fp32), Bh = bf16(x @ V2). fp32 VALU GEMM.
// ---------------------------------------------------------------------------
__global__ __launch_bounds__(256) void gemm_kernel(const float* __restrict__ x,
                                                   const float* __restrict__ V1,
                                                   const float* __restrict__ V2,
                                                   const float* __restrict__ bias,
                                                   float* __restrict__ A,
                                                   unsigned short* __restrict__ Bh,
                                                   int n_nodes) {
    __shared__ float xs[32][N_CH];      // 16 KB
    const int n0 = blockIdx.x * 32;
    const int tid = threadIdx.x;

    if (n0 + 32 <= n_nodes) {
        const float4* xg = (const float4*)(x + (size_t)n0 * N_CH);
        float4* xsv = (float4*)&xs[0][0];
        #pragma unroll
        for (int i = 0; i < 4; ++i) xsv[tid + i * 256] = xg[tid + i * 256];
    } else {
        for (int i = tid; i < 32 * N_CH; i += 256) {
            int n = n0 + (i >> 7);
            (&xs[0][0])[i] = (n < n_nodes) ? x[(size_t)n * N_CH + (i & 127)] : 0.f;
        }
    }
    __syncthreads();

    const int o  = tid & 127;
    const int nh = tid >> 7;            // 0 or 1
    const float bo = bias[o];
    float acc1[16], acc2[16];
    #pragma unroll
    for (int i = 0; i < 16; ++i) { acc1[i] = 0.f; acc2[i] = 0.f; }

    const float* xrow = &xs[nh * 16][0];
    for (int k4 = 0; k4 < N_CH; k4 += 4) {
        float w1[4], w2[4];
        #pragma unroll
        for (int j = 0; j < 4; ++j) {
            w1[j] = V1[(k4 + j) * N_CH + o];
            w2[j] = V2[(k4 + j) * N_CH + o];
        }
        #pragma unroll
        for (int i = 0; i < 16; ++i) {
            float4 xv = *(const float4*)&xrow[i * N_CH + k4];
            acc1[i] = fmaf(xv.x, w1[0], acc1[i]); acc2[i] = fmaf(xv.x, w2[0], acc2[i]);
            acc1[i] = fmaf(xv.y, w1[1], acc1[i]); acc2[i] = fmaf(xv.y, w2[1], acc2[i]);
            acc1[i] = fmaf(xv.z, w1[2], acc1[i]); acc2[i] = fmaf(xv.z, w2[2], acc2[i]);
            acc1[i] = fmaf(xv.w, w1[3], acc1[i]); acc2[i] = fmaf(xv.w, w2[3], acc2[i]);
        }
    }

    #pragma unroll
    for (int i = 0; i < 16; ++i) {
        int n = n0 + nh * 16 + i;
        if (n < n_nodes) {
            A[(size_t)n * N_CH + o] = acc1[i] + bo;
            // bf16 round-to-nearest-even
            unsigned int bits = __float_as_uint(acc2[i]);
            unsigned int r = (bits + 0x7FFFu + ((bits >> 16) & 1u)) >> 16;
            Bh[(size_t)n * N_CH + o] = (unsigned short)r;
        }
    }
}

// ---------------------------------------------------------------------------
// K2: bucket histogram (bucket = dst >> 5). LDS-staged.
// ---------------------------------------------------------------------------
__global__ __launch_bounds__(256) void bhist_kernel(const int* __restrict__ dst,
                                                    int* __restrict__ binCount,
                                                    int n_edges, int nb) {
    __shared__ int h[NB_MAX];
    const int tid = threadIdx.x;
    for (int i = tid; i < nb; i += 256) h[i] = 0;
    __syncthreads();
    const int base = blockIdx.x * BIN_CHUNK;
    const int cnt = min(BIN_CHUNK, n_edges - base);
    for (int j = tid; j < cnt; j += 256)
        atomicAdd(&h[dst[base + j] >> 5], 1);
    __syncthreads();
    for (int i = tid; i < nb; i += 256)
        if (h[i]) atomicAdd(&binCount[i], h[i]);
}

// ---------------------------------------------------------------------------
// K3: exclusive scan over nb (<=512) bucket counts -> binOff[nb+1], binCursor
// ---------------------------------------------------------------------------
__global__ __launch_bounds__(512) void bscan_kernel(const int* __restrict__ binCount,
                                                    int* __restrict__ binOff,
                                                    int* __restrict__ binCursor,
                                                    int nb) {
    __shared__ int t[512];
    const int tid = threadIdx.x;
    int v = (tid < nb) ? binCount[tid] : 0;
    t[tid] = v;
    __syncthreads();
    #pragma unroll
    for (int off = 1; off < 512; off <<= 1) {
        int u = (tid >= off) ? t[tid - off] : 0;
        __syncthreads();
        t[tid] += u;
        __syncthreads();
    }
    if (tid < nb) {
        int excl = t[tid] - v;
        binOff[tid] = excl;
        binCursor[tid] = excl;
    }
    if (tid == 0) binOff[nb] = t[nb - 1];
}

// ---------------------------------------------------------------------------
// K4: bin scatter. Counting-sort BIN_CHUNK edges by bucket in LDS, reserve
// per-bucket global ranges, write packed (dst&31)<<14 | src in ordered runs.
// Requires n_nodes < 16384.
// ---------------------------------------------------------------------------
__global__ __launch_bounds__(BIN_T) void bin_kernel(const int* __restrict__ src,
                                                    const int* __restrict__ dst,
                                                    int* __restrict__ binCursor,
                                                    unsigned int* __restrict__ binned,
                                                    int n_edges, int nb) {
    __shared__ unsigned int   lpk[BIN_CHUNK];      // 16 KB
    __shared__ unsigned short lbk[BIN_CHUNK];      // 8 KB
    __shared__ int sc[512];
    __shared__ int lhist[NB_MAX], lexcl[NB_MAX], lcur[NB_MAX], bbase[NB_MAX];

    const int tid = threadIdx.x;
    const int base = blockIdx.x * BIN_CHUNK;
    const int cnt = min(BIN_CHUNK, n_edges - base);

    for (int i = tid; i < nb; i += BIN_T) lhist[i] = 0;
    __syncthreads();

    unsigned int vreg[BIN_CHUNK / BIN_T];
    unsigned short breg[BIN_CHUNK / BIN_T];
    int nloc = 0;
    for (int j = tid; j < cnt; j += BIN_T) {
        int s = src[base + j];
        int d = dst[base + j];
        int b = d >> 5;
        vreg[nloc] = ((unsigned int)(d & 31) << 14) | (unsigned int)s;
        breg[nloc] = (unsigned short)b;
        ++nloc;
        atomicAdd(&lhist[b], 1);
    }
    __syncthreads();

    int v = (tid < nb) ? lhist[tid] : 0;
    sc[tid] = v;
    __syncthreads();
    #pragma unroll
    for (int off = 1; off < 512; off <<= 1) {
        int u = (tid >= off) ? sc[tid - off] : 0;
        __syncthreads();
        sc[tid] += u;
        __syncthreads();
    }
    if (tid < nb) {
        int excl = sc[tid] - v;
        lexcl[tid] = excl;
        lcur[tid] = excl;
    }
    __syncthreads();

    for (int k = 0; k < nloc; ++k) {
        int b = breg[k];
        int p = atomicAdd(&lcur[b], 1);
        lpk[p] = vreg[k];
        lbk[p] = (unsigned short)b;
    }
    __syncthreads();

    for (int b = tid; b < nb; b += BIN_T) {
        int c = lhist[b];
        if (c) bbase[b] = atomicAdd(&binCursor[b], c);
    }
    __syncthreads();

    for (int i = tid; i < cnt; i += BIN_T) {
        int b = lbk[i];
        binned[bbase[b] + (i - lexcl[b])] = lpk[i];
    }
}

// ---------------------------------------------------------------------------
// K5: fused CSR-build + gather-max. One block per bucket (32 nodes).
// Per 4096-edge chunk: counting-sort window by dst&31 in LDS (32 bins),
// 4 groups of 128 lanes stream sorted runs with register max accumulation,
// flush per-run via LDS atomicMax on order-preserving uint keys.
// Epilogue: out = A' + max (A' has bias folded); untouched acc -> 0.
// ---------------------------------------------------------------------------
__global__ __launch_bounds__(BM_T) void bucketmax_kernel(
        const unsigned int* __restrict__ binned,
        const int* __restrict__ binOff,
        const float* __restrict__ A,
        const unsigned short* __restrict__ Bh,
        float* __restrict__ out,
        int n_nodes) {
    __shared__ unsigned int sidx[BM_CAP];          // 16 KB sorted window
    __shared__ unsigned int accU[32 * N_CH];       // 16 KB max-key accum
    __shared__ int lhist[32], lexcl[32], lcur[32];

    const int b = blockIdx.x;
    const int tid = threadIdx.x;
    const int rbeg = binOff[b], rend = binOff[b + 1];

    for (int i = tid; i < 32 * N_CH; i += BM_T) accU[i] = NEG_INF_KEY;

    for (int cbeg = rbeg; cbeg < rend; cbeg += BM_CAP) {
        const int cnt = min(BM_CAP, rend - cbeg);
        if (tid < 32) lhist[tid] = 0;
        __syncthreads();                       // covers accU init too
        for (int j = tid; j < cnt; j += BM_T)
            atomicAdd(&lhist[binned[cbeg + j] >> 14], 1);
        __syncthreads();
        if (tid == 0) {
            int s = 0;
            #pragma unroll
            for (int k = 0; k < 32; ++k) { lexcl[k] = s; lcur[k] = s; s += lhist[k]; }
        }
        __syncthreads();
        for (int j = tid; j < cnt; j += BM_T) {
            unsigned int w = binned[cbeg + j];
            int p = atomicAdd(&lcur[w >> 14], 1);
            sidx[p] = w;
        }
        __syncthreads();

        const int g  = tid >> 7;               // 4 groups of 128 lanes
        const int gc = tid & 127;
        const int per = (cnt + 3) >> 2;
        const int gb = g * per;
        const int ge = min(cnt, gb + per);
        float run = -INFINITY;
        int cur = -1;
        for (int i = gb; i < ge; i += 4) {
            const int lim = min(4, ge - i);
            unsigned int w[4];
            float v[4];
            for (int j = 0; j < lim; ++j) w[j] = sidx[i + j];          // broadcast
            for (int j = 0; j < lim; ++j) {
                unsigned short h = Bh[(size_t)(w[j] & 16383u) * N_CH + gc];
                v[j] = __uint_as_float((unsigned int)h << 16);
            }
            for (int j = 0; j < lim; ++j) {
                int d5 = (int)(w[j] >> 14);
                if (d5 != cur) {                                        // uniform branch
                    if (cur >= 0) atomicMax(&accU[cur * N_CH + gc], fkey(run));
                    cur = d5;
                    run = -INFINITY;
                }
                run = fmaxf(run, v[j]);
            }
        }
        if (cur >= 0) atomicMax(&accU[cur * N_CH + gc], fkey(run));
        __syncthreads();
    }

    // epilogue: 32 nodes x 128 ch, coalesced
    for (int i = tid; i < 32 * N_CH; i += BM_T) {
        int node = b * 32 + (i >> 7);
        if (node < n_nodes) {
            unsigned int k = accU[i];
            float r = 0.f;
            if (k != NEG_INF_KEY)
                r = A[(size_t)node * N_CH + (i & 127)] + keyf(k);
            out[(size_t)node * N_CH + (i & 127)] = r;
        }
    }
}

// ---------------------------------------------------------------------------
extern "C" void kernel_launch(void* const* d_in, const int* in_sizes, int n_in,
                              void* d_out, int out_size, void* d_ws, size_t ws_size,
                              hipStream_t stream) {
    const float* x = (const float*)d_in[0];
    const float* W = (const float*)d_in[1];
    const float* b = (const float*)d_in[2];
    const int*   ei = (const int*)d_in[3];

    const int n_nodes = in_sizes[0] / N_CH;   // 10000
    const int n_edges = in_sizes[3] / 2;      // 640000
    const int nb = (n_nodes + 31) >> 5;       // 313 buckets of 32 nodes
    const int* src = ei;
    const int* dst = ei + n_edges;
    float* out = (float*)d_out;

    char* ws = (char*)d_ws;
    size_t off = 0;
    auto alloc = [&](size_t bytes) -> void* {
        void* p = ws + off;
        off += (bytes + 255) & ~(size_t)255;
        return p;
    };
    float* V1        = (float*)alloc((size_t)N_CH * N_CH * 4);
    float* V2        = (float*)alloc((size_t)N_CH * N_CH * 4);
    float* A         = (float*)alloc((size_t)n_nodes * N_CH * 4);
    unsigned short* Bh = (unsigned short*)alloc((size_t)n_nodes * N_CH * 2);
    int*   binCount  = (int*)alloc((size_t)nb * 4);
    int*   binOff    = (int*)alloc((size_t)(nb + 1) * 4);
    int*   binCursor = (int*)alloc((size_t)nb * 4);
    unsigned int* binned = (unsigned int*)alloc((size_t)n_edges * 4);
    (void)ws_size; (void)n_in; (void)out_size;

    const int nbin_blocks = (n_edges + BIN_CHUNK - 1) / BIN_CHUNK;

    prep_kernel <<<(N_CH * N_CH + 255) / 256, 256, 0, stream>>>(W, V1, V2, binCount, nb);
    gemm_kernel <<<(n_nodes + 31) / 32, 256, 0, stream>>>(x, V1, V2, b, A, Bh, n_nodes);
    bhist_kernel<<<nbin_blocks, 256, 0, stream>>>(dst, binCount, n_edges, nb);
    bscan_kernel<<<1, 512, 0, stream>>>(binCount, binOff, binCursor, nb);
    bin_kernel  <<<nbin_blocks, BIN_T, 0, stream>>>(src, dst, binCursor, binned, n_edges, nb);
    bucketmax_kernel<<<nb, BM_T, 0, stream>>>(binned, binOff, A, Bh, out, n_nodes);
}

// Round 4
// 138.463 us; speedup vs baseline: 2.6623x; 2.6623x over previous
//
#include <hip/hip_runtime.h>
#include <math.h>

#define N_CH 128
#define NB_MAX 512          // max bucket count (n_nodes <= 16384 -> nb <= 512)
#define BIN_CHUNK 4096
#define BIN_T 512

// ---------------------------------------------------------------------------
// K0: V1t[k*128+o] = W[o][k] - W[o][128+k], V2t[k*128+o] = W[o][128+k];
//     zero bucket histogram.
// ---------------------------------------------------------------------------
__global__ __launch_bounds__(256) void prep_kernel(const float* __restrict__ W,
                                                   float* __restrict__ V1,
                                                   float* __restrict__ V2,
                                                   int* __restrict__ binCount,
                                                   int nb) {
    int i = blockIdx.x * 256 + threadIdx.x;
    if (i < N_CH * N_CH) {
        int k = i >> 7, o = i & 127;
        float w1 = W[o * 256 + k];
        float w2 = W[o * 256 + 128 + k];
        V1[i] = w1 - w2;
        V2[i] = w2;
    }
    if (i < nb) binCount[i] = 0;
}

// ---------------------------------------------------------------------------
// K1: A = x @ V1 + bias (fp32), Bh = bf16(x @ V2). fp32 VALU GEMM.
// ---------------------------------------------------------------------------
__global__ __launch_bounds__(256) void gemm_kernel(const float* __restrict__ x,
                                                   const float* __restrict__ V1,
                                                   const float* __restrict__ V2,
                                                   const float* __restrict__ bias,
                                                   float* __restrict__ A,
                                                   unsigned short* __restrict__ Bh,
                                                   int n_nodes) {
    __shared__ float xs[32][N_CH];      // 16 KB
    const int n0 = blockIdx.x * 32;
    const int tid = threadIdx.x;

    if (n0 + 32 <= n_nodes) {
        const float4* xg = (const float4*)(x + (size_t)n0 * N_CH);
        float4* xsv = (float4*)&xs[0][0];
        #pragma unroll
        for (int i = 0; i < 4; ++i) xsv[tid + i * 256] = xg[tid + i * 256];
    } else {
        for (int i = tid; i < 32 * N_CH; i += 256) {
            int n = n0 + (i >> 7);
            (&xs[0][0])[i] = (n < n_nodes) ? x[(size_t)n * N_CH + (i & 127)] : 0.f;
        }
    }
    __syncthreads();

    const int o  = tid & 127;
    const int nh = tid >> 7;            // 0 or 1
    const float bo = bias[o];
    float acc1[16], acc2[16];
    #pragma unroll
    for (int i = 0; i < 16; ++i) { acc1[i] = 0.f; acc2[i] = 0.f; }

    const float* xrow = &xs[nh * 16][0];
    for (int k4 = 0; k4 < N_CH; k4 += 4) {
        float w1[4], w2[4];
        #pragma unroll
        for (int j = 0; j < 4; ++j) {
            w1[j] = V1[(k4 + j) * N_CH + o];
            w2[j] = V2[(k4 + j) * N_CH + o];
        }
        #pragma unroll
        for (int i = 0; i < 16; ++i) {
            float4 xv = *(const float4*)&xrow[i * N_CH + k4];
            acc1[i] = fmaf(xv.x, w1[0], acc1[i]); acc2[i] = fmaf(xv.x, w2[0], acc2[i]);
            acc1[i] = fmaf(xv.y, w1[1], acc1[i]); acc2[i] = fmaf(xv.y, w2[1], acc2[i]);
            acc1[i] = fmaf(xv.z, w1[2], acc1[i]); acc2[i] = fmaf(xv.z, w2[2], acc2[i]);
            acc1[i] = fmaf(xv.w, w1[3], acc1[i]); acc2[i] = fmaf(xv.w, w2[3], acc2[i]);
        }
    }

    #pragma unroll
    for (int i = 0; i < 16; ++i) {
        int n = n0 + nh * 16 + i;
        if (n < n_nodes) {
            A[(size_t)n * N_CH + o] = acc1[i] + bo;
            // bf16 round-to-nearest-even
            unsigned int bits = __float_as_uint(acc2[i]);
            unsigned int r = (bits + 0x7FFFu + ((bits >> 16) & 1u)) >> 16;
            Bh[(size_t)n * N_CH + o] = (unsigned short)r;
        }
    }
}

// ---------------------------------------------------------------------------
// K2: bucket histogram (bucket = dst >> 5). LDS-staged.
// ---------------------------------------------------------------------------
__global__ __launch_bounds__(256) void bhist_kernel(const int* __restrict__ dst,
                                                    int* __restrict__ binCount,
                                                    int n_edges, int nb) {
    __shared__ int h[NB_MAX];
    const int tid = threadIdx.x;
    for (int i = tid; i < nb; i += 256) h[i] = 0;
    __syncthreads();
    const int base = blockIdx.x * BIN_CHUNK;
    const int cnt = min(BIN_CHUNK, n_edges - base);
    for (int j = tid; j < cnt; j += 256)
        atomicAdd(&h[dst[base + j] >> 5], 1);
    __syncthreads();
    for (int i = tid; i < nb; i += 256)
        if (h[i]) atomicAdd(&binCount[i], h[i]);
}

// ---------------------------------------------------------------------------
// K3: exclusive scan over nb (<=512) bucket counts -> binOff[nb+1], binCursor
// ---------------------------------------------------------------------------
__global__ __launch_bounds__(512) void bscan_kernel(const int* __restrict__ binCount,
                                                    int* __restrict__ binOff,
                                                    int* __restrict__ binCursor,
                                                    int nb) {
    __shared__ int t[512];
    const int tid = threadIdx.x;
    int v = (tid < nb) ? binCount[tid] : 0;
    t[tid] = v;
    __syncthreads();
    #pragma unroll
    for (int off = 1; off < 512; off <<= 1) {
        int u = (tid >= off) ? t[tid - off] : 0;
        __syncthreads();
        t[tid] += u;
        __syncthreads();
    }
    if (tid < nb) {
        int excl = t[tid] - v;
        binOff[tid] = excl;
        binCursor[tid] = excl;
    }
    if (tid == 0) binOff[nb] = t[nb - 1];
}

// ---------------------------------------------------------------------------
// K4: bin scatter. Counting-sort BIN_CHUNK edges by bucket in LDS, reserve
// per-bucket global ranges, write packed (dst&31)<<14 | src in ordered runs.
// Requires n_nodes < 16384.
// ---------------------------------------------------------------------------
__global__ __launch_bounds__(BIN_T) void bin_kernel(const int* __restrict__ src,
                                                    const int* __restrict__ dst,
                                                    int* __restrict__ binCursor,
                                                    unsigned int* __restrict__ binned,
                                                    int n_edges, int nb) {
    __shared__ unsigned int   lpk[BIN_CHUNK];      // 16 KB
    __shared__ unsigned short lbk[BIN_CHUNK];      // 8 KB
    __shared__ int sc[512];
    __shared__ int lhist[NB_MAX], lexcl[NB_MAX], lcur[NB_MAX], bbase[NB_MAX];

    const int tid = threadIdx.x;
    const int base = blockIdx.x * BIN_CHUNK;
    const int cnt = min(BIN_CHUNK, n_edges - base);

    for (int i = tid; i < nb; i += BIN_T) lhist[i] = 0;
    __syncthreads();

    unsigned int vreg[BIN_CHUNK / BIN_T];
    unsigned short breg[BIN_CHUNK / BIN_T];
    int nloc = 0;
    for (int j = tid; j < cnt; j += BIN_T) {
        int s = src[base + j];
        int d = dst[base + j];
        int b = d >> 5;
        vreg[nloc] = ((unsigned int)(d & 31) << 14) | (unsigned int)s;
        breg[nloc] = (unsigned short)b;
        ++nloc;
        atomicAdd(&lhist[b], 1);
    }
    __syncthreads();

    int v = (tid < nb) ? lhist[tid] : 0;
    sc[tid] = v;
    __syncthreads();
    #pragma unroll
    for (int off = 1; off < 512; off <<= 1) {
        int u = (tid >= off) ? sc[tid - off] : 0;
        __syncthreads();
        sc[tid] += u;
        __syncthreads();
    }
    if (tid < nb) {
        int excl = sc[tid] - v;
        lexcl[tid] = excl;
        lcur[tid] = excl;
    }
    __syncthreads();

    for (int k = 0; k < nloc; ++k) {
        int b = breg[k];
        int p = atomicAdd(&lcur[b], 1);
        lpk[p] = vreg[k];
        lbk[p] = (unsigned short)b;
    }
    __syncthreads();

    for (int b = tid; b < nb; b += BIN_T) {
        int c = lhist[b];
        if (c) bbase[b] = atomicAdd(&binCursor[b], c);
    }
    __syncthreads();

    for (int i = tid; i < cnt; i += BIN_T) {
        int b = lbk[i];
        binned[bbase[b] + (i - lexcl[b])] = lpk[i];
    }
}

// ---------------------------------------------------------------------------
// K5: per-bucket CSR build. One block per bucket (32 nodes): local hist/scan
// in LDS, eidx scatter confined to the bucket's contiguous ~8 KB window,
// global offsets[] emitted directly.
// ---------------------------------------------------------------------------
__global__ __launch_bounds__(256) void build_kernel(const unsigned int* __restrict__ binned,
                                                    const int* __restrict__ binOff,
                                                    int* __restrict__ offsets,
                                                    int* __restrict__ eidx,
                                                    int n_nodes, int nb) {
    __shared__ int lhist[32], lexcl[33], lcur[32];
    const int b = blockIdx.x;
    const int tid = threadIdx.x;
    const int rbeg = binOff[b], rend = binOff[b + 1];

    if (tid < 32) { lhist[tid] = 0; lcur[tid] = 0; }
    __syncthreads();
    for (int i = rbeg + tid; i < rend; i += 256)
        atomicAdd(&lhist[binned[i] >> 14], 1);
    __syncthreads();
    if (tid == 0) {
        int s = 0;
        for (int k = 0; k < 32; ++k) { lexcl[k] = s; s += lhist[k]; }
        lexcl[32] = s;
    }
    __syncthreads();
    if (tid < 32) {
        int n = b * 32 + tid;
        if (n < n_nodes) offsets[n] = rbeg + lexcl[tid];
    }
    if (b == nb - 1 && tid == 0) offsets[n_nodes] = rend;
    for (int i = rbeg + tid; i < rend; i += 256) {
        unsigned int w = binned[i];
        int d5 = (int)(w >> 14);
        int r = atomicAdd(&lcur[d5], 1);
        eidx[rbeg + lexcl[d5] + r] = (int)(w & 16383u);
    }
}

// ---------------------------------------------------------------------------
// K6: per-node gather-max. One WAVE (64 lanes) per node, 4 nodes per block.
// Lane l covers channels 2l, 2l+1 packed in one uint of Bh (bf16 pair).
// Wave-synchronous LDS index staging (single wave -> no __syncthreads).
// Epilogue: out = A' + max (bias pre-folded in A'); isolated nodes -> 0.
// ---------------------------------------------------------------------------
__global__ __launch_bounds__(256) void gather_kernel(
        const float* __restrict__ A,
        const unsigned int* __restrict__ Bh2,   // n_nodes x 64 uints
        const int* __restrict__ offsets,
        const int* __restrict__ eidx,
        float* __restrict__ out,
        int n_nodes) {
    __shared__ int sidx[4][64];
    const int g = threadIdx.x >> 6;
    const int l = threadIdx.x & 63;
    const int n = blockIdx.x * 4 + g;
    if (n >= n_nodes) return;
    const int beg = offsets[n], end = offsets[n + 1];

    float mlo[8], mhi[8];
    #pragma unroll
    for (int i = 0; i < 8; ++i) { mlo[i] = -INFINITY; mhi[i] = -INFINITY; }

    for (int base = beg; base < end; base += 64) {
        int p = base + l;
        if (p < end) sidx[g][l] = eidx[p];
        // single-wave lockstep: compiler's lgkmcnt wait orders write->read
        int cnt = min(64, end - base);
        int q = 0;
        for (; q + 8 <= cnt; q += 8) {
            unsigned int w[8];
            #pragma unroll
            for (int i = 0; i < 8; ++i)
                w[i] = Bh2[(size_t)sidx[g][q + i] * 64 + l];
            #pragma unroll
            for (int i = 0; i < 8; ++i) {
                mlo[i] = fmaxf(mlo[i], __uint_as_float(w[i] << 16));
                mhi[i] = fmaxf(mhi[i], __uint_as_float(w[i] & 0xFFFF0000u));
            }
        }
        for (; q < cnt; ++q) {
            unsigned int w = Bh2[(size_t)sidx[g][q] * 64 + l];
            mlo[0] = fmaxf(mlo[0], __uint_as_float(w << 16));
            mhi[0] = fmaxf(mhi[0], __uint_as_float(w & 0xFFFF0000u));
        }
    }

    float lo = mlo[0], hi = mhi[0];
    #pragma unroll
    for (int i = 1; i < 8; ++i) { lo = fmaxf(lo, mlo[i]); hi = fmaxf(hi, mhi[i]); }

    float2 r = make_float2(0.f, 0.f);
    if (end > beg) {
        float2 a = *(const float2*)(A + (size_t)n * N_CH + 2 * l);
        r.x = a.x + lo;
        r.y = a.y + hi;
    }
    *(float2*)(out + (size_t)n * N_CH + 2 * l) = r;
}

// ---------------------------------------------------------------------------
extern "C" void kernel_launch(void* const* d_in, const int* in_sizes, int n_in,
                              void* d_out, int out_size, void* d_ws, size_t ws_size,
                              hipStream_t stream) {
    const float* x = (const float*)d_in[0];
    const float* W = (const float*)d_in[1];
    const float* b = (const float*)d_in[2];
    const int*   ei = (const int*)d_in[3];

    const int n_nodes = in_sizes[0] / N_CH;   // 10000
    const int n_edges = in_sizes[3] / 2;      // 640000
    const int nb = (n_nodes + 31) >> 5;       // 313 buckets of 32 nodes
    const int* src = ei;
    const int* dst = ei + n_edges;
    float* out = (float*)d_out;

    char* ws = (char*)d_ws;
    size_t off = 0;
    auto alloc = [&](size_t bytes) -> void* {
        void* p = ws + off;
        off += (bytes + 255) & ~(size_t)255;
        return p;
    };
    float* V1        = (float*)alloc((size_t)N_CH * N_CH * 4);
    float* V2        = (float*)alloc((size_t)N_CH * N_CH * 4);
    float* A         = (float*)alloc((size_t)n_nodes * N_CH * 4);
    unsigned short* Bh = (unsigned short*)alloc((size_t)n_nodes * N_CH * 2);
    int*   binCount  = (int*)alloc((size_t)nb * 4);
    int*   binOff    = (int*)alloc((size_t)(nb + 1) * 4);
    int*   binCursor = (int*)alloc((size_t)nb * 4);
    unsigned int* binned = (unsigned int*)alloc((size_t)n_edges * 4);
    int*   offsets   = (int*)alloc((size_t)(n_nodes + 1) * 4);
    int*   eidx      = (int*)alloc((size_t)n_edges * 4);
    (void)ws_size; (void)n_in; (void)out_size;

    const int nbin_blocks = (n_edges + BIN_CHUNK - 1) / BIN_CHUNK;

    prep_kernel <<<(N_CH * N_CH + 255) / 256, 256, 0, stream>>>(W, V1, V2, binCount, nb);
    gemm_kernel <<<(n_nodes + 31) / 32, 256, 0, stream>>>(x, V1, V2, b, A, Bh, n_nodes);
    bhist_kernel<<<nbin_blocks, 256, 0, stream>>>(dst, binCount, n_edges, nb);
    bscan_kernel<<<1, 512, 0, stream>>>(binCount, binOff, binCursor, nb);
    bin_kernel  <<<nbin_blocks, BIN_T, 0, stream>>>(src, dst, binCursor, binned, n_edges, nb);
    build_kernel<<<nb, 256, 0, stream>>>(binned, binOff, offsets, eidx, n_nodes, nb);
    gather_kernel<<<(n_nodes + 3) / 4, 256, 0, stream>>>(A, (const unsigned int*)Bh, offsets, eidx, out, n_nodes);
}